// Round 3
// baseline (494.765 us; speedup 1.0000x reference)
//
#include <hip/hip_runtime.h>

#define DECAYF 0.99f
#define ONEMF 0.01f
#define EPSF 1e-5f

typedef __bf16 bf16x8 __attribute__((ext_vector_type(8)));
typedef float f32x4 __attribute__((ext_vector_type(4)));
typedef unsigned short ushort8 __attribute__((ext_vector_type(8)));

// ws layout (float indices):
// [0,65536)        dw accumulator (K*D)
// [65536,66560)    counts (K)
// [66560,67584)    nchalf = -0.5*||e_k||^2
// [67584]          sse
// [67600,100368)   E_hi as bf16 (ushort), row-major [K][D]
// [100368,133136)  E_lo as bf16 (ushort)
#define WS_COUNTS 65536
#define WS_NCHALF 66560
#define WS_SSE    67584
#define WS_EHI    67600
#define WS_ELO    100368

__device__ __forceinline__ float wave_reduce_add(float v) {
#pragma unroll
    for (int o = 32; o > 0; o >>= 1) v += __shfl_xor(v, o, 64);
    return v;
}

__device__ __forceinline__ unsigned short bf_rne(float f) {
    unsigned int u = __float_as_uint(f);
    unsigned int r = u + 0x7fffu + ((u >> 16) & 1u);
    return (unsigned short)(r >> 16);
}

// Streaming zero-fill of one-hot encodings + (blocks 0..255) prep work:
// zero dw/counts/sse, split E into bf16 hi/lo, nchalf. grid 2048 x 256.
__global__ __launch_bounds__(256) void fill_prep(const float* __restrict__ E,
                                                 float* __restrict__ out,
                                                 float* __restrict__ ws) {
    const int bid = blockIdx.x, tid = threadIdx.x;
    // ---- one-hot zero fill (all 2048 blocks) ----
    float* enc = out + 1 + (size_t)4194304;
    const size_t base = ((size_t)bid * 256 + (size_t)tid) * 4;
    const f32x4 z = {0.0f, 0.0f, 0.0f, 0.0f};
#pragma unroll
    for (int i = 0; i < 32; ++i) {
        __builtin_nontemporal_store(z, (f32x4*)(enc + base + (size_t)i * 2097152));
    }
    // ---- prep (blocks 0..255): each block handles 256 elements of E ----
    if (bid < 256) {
        const int id = bid * 256 + tid;        // k = id>>6, c = id&63
        ws[id] = 0.0f;                         // dw accumulator zero
        if (bid < 4) ws[WS_COUNTS + bid * 256 + tid] = 0.0f;
        if (bid == 4 && tid == 0) ws[WS_SSE] = 0.0f;
        const float v = E[id];
        const unsigned short h = bf_rne(v);
        const float hf = __uint_as_float((unsigned int)h << 16);
        const unsigned short l = bf_rne(v - hf);
        ((unsigned short*)(ws + WS_EHI))[id] = h;
        ((unsigned short*)(ws + WS_ELO))[id] = l;
        const float s = wave_reduce_add(v * v);   // one E-row per wave
        if ((tid & 63) == 0) ws[WS_NCHALF + (id >> 6)] = -0.5f * s;
    }
}

// Main: MFMA scores + top-2 + fp64 re-rank + scatter outputs.
// grid 1024 x 256; each block = 64 tokens (16 tokens per wave) for 2x occupancy
// vs the old 128-token/512-block config (latency-bound at 8 waves/CU).
__global__ __launch_bounds__(256, 4) void vq_main(const float* __restrict__ x,
                                                  const float* __restrict__ E,
                                                  float* __restrict__ out,
                                                  float* __restrict__ ws) {
    const int tid = threadIdx.x;
    const int lane = tid & 63;
    const int w = tid >> 6;
    const int blk = blockIdx.x;
    const int b = blk >> 6;            // batch (64 blocks per batch)
    const int hw0 = (blk & 63) << 6;   // hw offset (64 tokens)
    const int tok0 = blk << 6;

    __shared__ float xs[64 * 68];      // [token][dim], stride 68 keeps rows 16B-aligned
    __shared__ int i1sh[64], i2sh[64], idx_sh[64];

    // Stage x tile (coalesced: consecutive tid -> consecutive hw).
    {
        const float* xb = x + ((size_t)b << 18) + hw0;
#pragma unroll
        for (int cc = 0; cc < 16; ++cc) {
            const int id = cc * 256 + tid;
            const int c = id >> 6, t = id & 63;
            xs[t * 68 + c] = xb[((size_t)c << 12) + t];
        }
    }
    __syncthreads();

    const int q = lane >> 4, m = lane & 15;

    // A fragments: 1 row-tile (16 tokens) x 2 K-slices x (hi,lo).
    bf16x8 Ah[2], Al[2];
    {
        const int tok = w * 16 + m;
#pragma unroll
        for (int s = 0; s < 2; ++s) {
            const float* p = &xs[tok * 68 + s * 32 + q * 8];
            ushort8 hu, lu;
#pragma unroll
            for (int j = 0; j < 8; ++j) {
                const float f = p[j];
                const unsigned short h = bf_rne(f);
                const float hf = __uint_as_float((unsigned int)h << 16);
                hu[j] = h;
                lu[j] = bf_rne(f - hf);
            }
            Ah[s] = __builtin_bit_cast(bf16x8, hu);
            Al[s] = __builtin_bit_cast(bf16x8, lu);
        }
    }

    const ushort8* __restrict__ Ehp = (const ushort8*)(ws + WS_EHI);  // [K][8] groups of 8 dims
    const ushort8* __restrict__ Elp = (const ushort8*)(ws + WS_ELO);
    const float* __restrict__ ncp = ws + WS_NCHALF;

    // Per-lane running top-2 per C/D row.
    float b1[4], b2[4];
    int i1[4], i2[4];
#pragma unroll
    for (int r = 0; r < 4; ++r) { b1[r] = -1e30f; b2[r] = -1e30f; i1[r] = 0; i2[r] = 1; }

    // Depth-2 register prefetch of B fragments; this lane's col = m.
    ushort8 pbh0[2], pbh1[2], pbl0[2], pbl1[2];
    float pnc[2];
#pragma unroll
    for (int s = 0; s < 2; ++s) {
        const int code = s * 16 + m;
        pbh0[s] = Ehp[code * 8 + q];
        pbh1[s] = Ehp[code * 8 + 4 + q];
        pbl0[s] = Elp[code * 8 + q];
        pbl1[s] = Elp[code * 8 + 4 + q];
        pnc[s] = ncp[code];
    }

#define VQ_STEP(S, CK)                                                          \
    {                                                                           \
        const bf16x8 bh0 = __builtin_bit_cast(bf16x8, pbh0[S]);                 \
        const bf16x8 bh1 = __builtin_bit_cast(bf16x8, pbh1[S]);                 \
        const bf16x8 bl0 = __builtin_bit_cast(bf16x8, pbl0[S]);                 \
        const bf16x8 bl1 = __builtin_bit_cast(bf16x8, pbl1[S]);                 \
        const float nc = pnc[S];                                                \
        if ((CK) + 2 < 64) {                                                    \
            const int code = ((CK) + 2) * 16 + m;                               \
            pbh0[S] = Ehp[code * 8 + q];                                        \
            pbh1[S] = Ehp[code * 8 + 4 + q];                                    \
            pbl0[S] = Elp[code * 8 + q];                                        \
            pbl1[S] = Elp[code * 8 + 4 + q];                                    \
            pnc[S] = ncp[code];                                                 \
        }                                                                       \
        f32x4 acc = {nc, nc, nc, nc}; /* score = x.e - 0.5||e||^2 */            \
        acc = __builtin_amdgcn_mfma_f32_16x16x32_bf16(Ah[0], bh0, acc, 0, 0, 0);\
        acc = __builtin_amdgcn_mfma_f32_16x16x32_bf16(Ah[1], bh1, acc, 0, 0, 0);\
        acc = __builtin_amdgcn_mfma_f32_16x16x32_bf16(Al[0], bh0, acc, 0, 0, 0);\
        acc = __builtin_amdgcn_mfma_f32_16x16x32_bf16(Al[1], bh1, acc, 0, 0, 0);\
        acc = __builtin_amdgcn_mfma_f32_16x16x32_bf16(Ah[0], bl0, acc, 0, 0, 0);\
        acc = __builtin_amdgcn_mfma_f32_16x16x32_bf16(Ah[1], bl1, acc, 0, 0, 0);\
        const int idx = (CK) * 16 + m;                                          \
        _Pragma("unroll")                                                       \
        for (int r = 0; r < 4; ++r) {                                           \
            const float s = acc[r];                                             \
            const bool cA = s > b1[r];                                          \
            const bool cB = s > b2[r];                                          \
            b2[r] = cA ? b1[r] : (cB ? s : b2[r]);                              \
            i2[r] = cA ? i1[r] : (cB ? idx : i2[r]);                            \
            b1[r] = cA ? s : b1[r];                                             \
            i1[r] = cA ? idx : i1[r];                                           \
        }                                                                       \
    }

    for (int j = 0; j < 32; ++j) {
        VQ_STEP(0, 2 * j)
        VQ_STEP(1, 2 * j + 1)
    }
#undef VQ_STEP

    // Merge top-2 across the 16 lanes of each quad-group (cols of the row).
#pragma unroll
    for (int d = 1; d < 16; d <<= 1) {
#pragma unroll
        for (int r = 0; r < 4; ++r) {
            const float ob1 = __shfl_xor(b1[r], d, 64);
            const int   oi1 = __shfl_xor(i1[r], d, 64);
            const float ob2 = __shfl_xor(b2[r], d, 64);
            const int   oi2 = __shfl_xor(i2[r], d, 64);
            const bool wv = ob1 > b1[r];
            const float t1 = wv ? ob1 : b1[r]; const int ti1 = wv ? oi1 : i1[r];
            const float sA = wv ? b1[r] : ob1; const int siA = wv ? i1[r] : oi1;
            const float sB = wv ? ob2 : b2[r]; const int siB = wv ? oi2 : i2[r];
            const bool w2 = sB > sA;
            b1[r] = t1; i1[r] = ti1;
            b2[r] = w2 ? sB : sA; i2[r] = w2 ? siB : siA;
        }
    }
    if (m == 0) {   // quad leaders publish rows 4q+r of the tile
#pragma unroll
        for (int r = 0; r < 4; ++r) {
            const int tokL = w * 16 + q * 4 + r;
            i1sh[tokL] = i1[r];
            i2sh[tokL] = i2[r];
        }
    }

    // fp64 re-rank of the two candidates (same wave -> no barrier needed).
    float dval = 0.0f;
    if (lane < 16) {
        const int tokL = w * 16 + lane;
        const int I1 = i1sh[tokL], I2 = i2sh[tokL];
        const int ca = I1 < I2 ? I1 : I2;
        const int cb = I1 < I2 ? I2 : I1;
        const float* Ea = E + ca * 64;
        const float* Eb = E + cb * 64;
        const float* xr = &xs[tokL * 68];
        double sa = 0, ea = 0, sb = 0, eb = 0, x2 = 0;
#pragma unroll 8
        for (int c = 0; c < 64; ++c) {
            const double xv = (double)xr[c];
            const double va = (double)Ea[c], vb = (double)Eb[c];
            sa += xv * va; ea += va * va;
            sb += xv * vb; eb += vb * vb;
            x2 += xv * xv;
        }
        const double qa = ea - 2.0 * sa;
        const double qb = eb - 2.0 * sb;
        int best; double qq;
        if (qb < qa) { best = cb; qq = qb; } else { best = ca; qq = qa; }
        idx_sh[tokL] = best;
        float dd = (float)(qq + x2);
        dval = dd < 0.f ? 0.f : dd;
        atomicAdd(&ws[WS_COUNTS + best], 1.0f);
    }
    const float ssum = wave_reduce_add(dval);
    if (lane == 0) atomicAdd(&ws[WS_SSE], ssum);
    __syncthreads();

    // q_st output (reference order: x + (e - x)).
    float* outq = out + 1;
#pragma unroll
    for (int cc = 0; cc < 16; ++cc) {
        const int id = cc * 256 + tid;
        const int c = id >> 6, t = id & 63;
        const int kb = idx_sh[t];
        const float xv = xs[t * 68 + c];
        const float eq = E[kb * 64 + c];
        outq[((size_t)(b * 64 + c) << 12) + hw0 + t] = xv + (eq - xv);
    }
    // dw scatter-add: lane = dim (coalesced atomics), wave-uniform row.
#pragma unroll 4
    for (int tt = 0; tt < 16; ++tt) {
        const int t = w * 16 + tt;
        const int kb = idx_sh[t];
        atomicAdd(&ws[kb * 64 + lane], xs[t * 68 + lane]);
    }
    // one-hot encodings: region pre-zeroed by fill_prep; write only the 1.0 entries.
    {
        float* enc = out + 1 + (size_t)4194304;
        if (tid < 64) {
            const int kb = idx_sh[tid];
            __builtin_nontemporal_store(1.0f, enc + (size_t)(tok0 + tid) * 1024 + kb);
        }
    }
}

// new_cs (Laplace-smoothed) + loss. 1 block x 1024.
__global__ __launch_bounds__(1024) void fin_cs(const float* __restrict__ cs_in,
                                               float* __restrict__ out,
                                               const float* __restrict__ ws) {
    __shared__ float red[16];
    __shared__ float n_sh;
    const int tid = threadIdx.x;
    const float raw = cs_in[tid] * DECAYF + ONEMF * ws[WS_COUNTS + tid];
    const float s = wave_reduce_add(raw);
    if ((tid & 63) == 0) red[tid >> 6] = s;
    __syncthreads();
    if (tid == 0) {
        float n = 0.f;
#pragma unroll
        for (int i = 0; i < 16; ++i) n += red[i];
        n_sh = n;
        out[0] = 0.25f * ws[WS_SSE] * (1.0f / 4194304.0f);  // loss
    }
    __syncthreads();
    const float n = n_sh;
    out[71368705 + tid] = (raw + EPSF) / (n + 1024.0f * EPSF) * n;
}

// new_ema_weight and new_embedding. grid 256 x 256.
__global__ __launch_bounds__(256) void fin_w(const float* __restrict__ emaw,
                                             float* __restrict__ out,
                                             const float* __restrict__ ws) {
    const int i = blockIdx.x * 256 + threadIdx.x;
    const float val = emaw[i] * DECAYF + ONEMF * ws[i];
    out[71369729 + i] = val;                               // new_ema_weight
    const float cs = out[71368705 + (i >> 6)];             // new_cs (from fin_cs)
    out[71303169 + i] = val / cs;                          // new_embedding
}

extern "C" void kernel_launch(void* const* d_in, const int* in_sizes, int n_in,
                              void* d_out, int out_size, void* d_ws, size_t ws_size,
                              hipStream_t stream) {
    const float* x    = (const float*)d_in[0];   // [16,64,64,64]
    const float* E    = (const float*)d_in[1];   // [1024,64]
    const float* cs   = (const float*)d_in[2];   // [1024]
    const float* emaw = (const float*)d_in[3];   // [1024,64]
    float* out = (float*)d_out;
    float* ws  = (float*)d_ws;

    fill_prep<<<2048, 256, 0, stream>>>(E, out, ws);
    vq_main<<<1024, 256, 0, stream>>>(x, E, out, ws);
    fin_cs<<<1, 1024, 0, stream>>>(cs, out, ws);
    fin_w<<<256, 256, 0, stream>>>(emaw, out, ws);
}

// Round 4
// 385.998 us; speedup vs baseline: 1.2818x; 1.2818x over previous
//
#include <hip/hip_runtime.h>

#define DECAYF 0.99f
#define ONEMF 0.01f
#define EPSF 1e-5f

typedef __bf16 bf16x8 __attribute__((ext_vector_type(8)));
typedef float f32x4 __attribute__((ext_vector_type(4)));
typedef unsigned short ushort8 __attribute__((ext_vector_type(8)));

// ws layout (float indices):
// [0,65536)        dw accumulator (K*D)
// [65536,66560)    counts (K)
// [66560,67584)    nchalf = -0.5*||e_k||^2
// [67584]          sse
// [67600,100368)   E_hi as bf16 (ushort), row-major [K][D]
// [100368,133136)  E_lo as bf16 (ushort)
#define WS_COUNTS 65536
#define WS_NCHALF 66560
#define WS_SSE    67584
#define WS_EHI    67600
#define WS_ELO    100368

__device__ __forceinline__ float wave_reduce_add(float v) {
#pragma unroll
    for (int o = 32; o > 0; o >>= 1) v += __shfl_xor(v, o, 64);
    return v;
}

__device__ __forceinline__ unsigned short bf_rne(float f) {
    unsigned int u = __float_as_uint(f);
    unsigned int r = u + 0x7fffu + ((u >> 16) & 1u);
    return (unsigned short)(r >> 16);
}

// Zero dw/counts/sse; split E into bf16 hi/lo; nchalf. grid 256 x 256.
__global__ __launch_bounds__(256) void prep_kernel(const float* __restrict__ E,
                                                   float* __restrict__ ws) {
    const int bid = blockIdx.x, tid = threadIdx.x;
    const int id = bid * 256 + tid;            // element of E (k = id>>6, c = id&63)
    ws[id] = 0.0f;                             // dw
    if (bid < 4) ws[WS_COUNTS + bid * 256 + tid] = 0.0f;
    if (bid == 4 && tid == 0) ws[WS_SSE] = 0.0f;
    const float v = E[id];
    const unsigned short h = bf_rne(v);
    const float hf = __uint_as_float((unsigned int)h << 16);
    const unsigned short l = bf_rne(v - hf);
    ((unsigned short*)(ws + WS_EHI))[id] = h;
    ((unsigned short*)(ws + WS_ELO))[id] = l;
    const int lane = tid & 63;
    const float s = wave_reduce_add(v * v);
    if (lane == 0) ws[WS_NCHALF + (id >> 6)] = -0.5f * s;
}

// Main: MFMA scores + top-2 + fp64 re-rank + all scatter outputs.
// grid 512 x 256; each block = 128 tokens.
// One-hot zero-rows are NT-stored *inside* the K-loop (no idx dependency), so the
// mandatory 268 MB write stream drains concurrently with the latency-bound loop
// instead of serializing in a tail phase (R0: tail drain ~= 110 us exposed).
__global__ __launch_bounds__(256) void vq_main(const float* __restrict__ x,
                                               const float* __restrict__ E,
                                               float* __restrict__ out,
                                               float* __restrict__ ws) {
    const int tid = threadIdx.x;
    const int lane = tid & 63;
    const int w = tid >> 6;
    const int blk = blockIdx.x;
    const int b = blk >> 5;            // batch
    const int hw0 = (blk & 31) << 7;   // hw offset (128 tokens)
    const int tok0 = blk << 7;

    __shared__ float xs[128 * 68];     // [token][dim], stride 68 keeps rows 16B-aligned
    __shared__ int i1sh[128], i2sh[128], idx_sh[128];

    float* enc = out + 1 + (size_t)4194304;
    f32x4* encb4 = (f32x4*)(enc + (size_t)tok0 * 1024);   // this block's 512 KB enc region

    // Stage x tile (fully coalesced: consecutive tid -> consecutive hw).
    {
        const float* xb = x + ((size_t)b << 18) + hw0;
#pragma unroll
        for (int cc = 0; cc < 32; ++cc) {
            const int id = cc * 256 + tid;
            const int c = id >> 7, t = id & 127;
            xs[t * 68 + c] = xb[((size_t)c << 12) + t];
        }
    }
    __syncthreads();

    const int q = lane >> 4, m = lane & 15;

    // A fragments: 2 row-tiles (16 tokens each) x 2 K-slices x (hi,lo).
    bf16x8 Ah[2][2], Al[2][2];
#pragma unroll
    for (int t = 0; t < 2; ++t) {
        const int tok = w * 32 + t * 16 + m;
#pragma unroll
        for (int s = 0; s < 2; ++s) {
            const float* p = &xs[tok * 68 + s * 32 + q * 8];
            ushort8 hu, lu;
#pragma unroll
            for (int j = 0; j < 8; ++j) {
                const float f = p[j];
                const unsigned short h = bf_rne(f);
                const float hf = __uint_as_float((unsigned int)h << 16);
                hu[j] = h;
                lu[j] = bf_rne(f - hf);
            }
            Ah[t][s] = __builtin_bit_cast(bf16x8, hu);
            Al[t][s] = __builtin_bit_cast(bf16x8, lu);
        }
    }

    const ushort8* __restrict__ Ehp = (const ushort8*)(ws + WS_EHI);  // [K][8] groups of 8 dims
    const ushort8* __restrict__ Elp = (const ushort8*)(ws + WS_ELO);
    const float* __restrict__ ncp = ws + WS_NCHALF;

    // Per-lane running top-2 per C/D row (4 regs x 2 tiles).
    float b1[2][4], b2[2][4];
    int i1[2][4], i2[2][4];
#pragma unroll
    for (int t = 0; t < 2; ++t)
#pragma unroll
        for (int r = 0; r < 4; ++r) { b1[t][r] = -1e30f; b2[t][r] = -1e30f; i1[t][r] = 0; i2[t][r] = 1; }

    // Register double-buffered B fragments; this lane's col = m.
    ushort8 nb0h = Ehp[m * 8 + q];
    ushort8 nb1h = Ehp[m * 8 + 4 + q];
    ushort8 nb0l = Elp[m * 8 + q];
    ushort8 nb1l = Elp[m * 8 + 4 + q];
    float nnc = ncp[m];

    const f32x4 z4 = {0.0f, 0.0f, 0.0f, 0.0f};

    for (int ck = 0; ck < 64; ++ck) {
        const ushort8 c0h = nb0h, c1h = nb1h, c0l = nb0l, c1l = nb1l;
        const float nc = nnc;
        if (ck < 63) {
            const int code = (ck + 1) * 16 + m;
            nb0h = Ehp[code * 8 + q];
            nb1h = Ehp[code * 8 + 4 + q];
            nb0l = Elp[code * 8 + q];
            nb1l = Elp[code * 8 + 4 + q];
            nnc = ncp[code];
        }
        // Interleaved one-hot zero-fill: 2 x 16B NT stores per thread per iter
        // covers 64*512*16B = 512 KB = this block's 128 enc rows exactly.
        {
            const int zslot = ck * 512 + tid;
            __builtin_nontemporal_store(z4, encb4 + zslot);
            __builtin_nontemporal_store(z4, encb4 + zslot + 256);
        }
        const bf16x8 bh0 = __builtin_bit_cast(bf16x8, c0h);
        const bf16x8 bh1 = __builtin_bit_cast(bf16x8, c1h);
        const bf16x8 bl0 = __builtin_bit_cast(bf16x8, c0l);
        const bf16x8 bl1 = __builtin_bit_cast(bf16x8, c1l);
        const int idx = ck * 16 + m;
#pragma unroll
        for (int t = 0; t < 2; ++t) {
            f32x4 acc = {nc, nc, nc, nc};   // score = x.e - 0.5||e||^2
            acc = __builtin_amdgcn_mfma_f32_16x16x32_bf16(Ah[t][0], bh0, acc, 0, 0, 0);
            acc = __builtin_amdgcn_mfma_f32_16x16x32_bf16(Ah[t][1], bh1, acc, 0, 0, 0);
            acc = __builtin_amdgcn_mfma_f32_16x16x32_bf16(Al[t][0], bh0, acc, 0, 0, 0);
            acc = __builtin_amdgcn_mfma_f32_16x16x32_bf16(Al[t][1], bh1, acc, 0, 0, 0);
            acc = __builtin_amdgcn_mfma_f32_16x16x32_bf16(Ah[t][0], bl0, acc, 0, 0, 0);
            acc = __builtin_amdgcn_mfma_f32_16x16x32_bf16(Ah[t][1], bl1, acc, 0, 0, 0);
#pragma unroll
            for (int r = 0; r < 4; ++r) {
                const float s = acc[r];
                const bool cA = s > b1[t][r];
                const bool cB = s > b2[t][r];
                b2[t][r] = cA ? b1[t][r] : (cB ? s : b2[t][r]);
                i2[t][r] = cA ? i1[t][r] : (cB ? idx : i2[t][r]);
                b1[t][r] = cA ? s : b1[t][r];
                i1[t][r] = cA ? idx : i1[t][r];
            }
        }
    }

    // Merge top-2 across the 16 lanes of each quad-group (cols of the row).
#pragma unroll
    for (int d = 1; d < 16; d <<= 1) {
#pragma unroll
        for (int t = 0; t < 2; ++t)
#pragma unroll
            for (int r = 0; r < 4; ++r) {
                const float ob1 = __shfl_xor(b1[t][r], d, 64);
                const int   oi1 = __shfl_xor(i1[t][r], d, 64);
                const float ob2 = __shfl_xor(b2[t][r], d, 64);
                const int   oi2 = __shfl_xor(i2[t][r], d, 64);
                const bool wv = ob1 > b1[t][r];
                const float t1 = wv ? ob1 : b1[t][r]; const int ti1 = wv ? oi1 : i1[t][r];
                const float sA = wv ? b1[t][r] : ob1; const int siA = wv ? i1[t][r] : oi1;
                const float sB = wv ? ob2 : b2[t][r]; const int siB = wv ? oi2 : i2[t][r];
                const bool w2 = sB > sA;
                b1[t][r] = t1; i1[t][r] = ti1;
                b2[t][r] = w2 ? sB : sA; i2[t][r] = w2 ? siB : siA;
            }
    }
    if (m == 0) {   // quad leaders publish rows 4q+r of each tile
#pragma unroll
        for (int t = 0; t < 2; ++t)
#pragma unroll
            for (int r = 0; r < 4; ++r) {
                const int tokL = w * 32 + t * 16 + q * 4 + r;
                i1sh[tokL] = i1[t][r];
                i2sh[tokL] = i2[t][r];
            }
    }

    // fp64 re-rank of the two candidates (same wave -> no barrier needed).
    float dval = 0.0f;
    if (lane < 32) {
        const int tokL = w * 32 + lane;
        const int I1 = i1sh[tokL], I2 = i2sh[tokL];
        const int ca = I1 < I2 ? I1 : I2;
        const int cb = I1 < I2 ? I2 : I1;
        const float* Ea = E + ca * 64;
        const float* Eb = E + cb * 64;
        const float* xr = &xs[tokL * 68];
        double sa = 0, ea = 0, sb = 0, eb = 0, x2 = 0;
#pragma unroll 8
        for (int c = 0; c < 64; ++c) {
            const double xv = (double)xr[c];
            const double va = (double)Ea[c], vb = (double)Eb[c];
            sa += xv * va; ea += va * va;
            sb += xv * vb; eb += vb * vb;
            x2 += xv * xv;
        }
        const double qa = ea - 2.0 * sa;
        const double qb = eb - 2.0 * sb;
        int best; double qq;
        if (qb < qa) { best = cb; qq = qb; } else { best = ca; qq = qa; }
        idx_sh[tokL] = best;
        float dd = (float)(qq + x2);
        dval = dd < 0.f ? 0.f : dd;
        atomicAdd(&ws[WS_COUNTS + best], 1.0f);
    }
    const float ssum = wave_reduce_add(dval);
    if (lane == 0) atomicAdd(&ws[WS_SSE], ssum);
    __syncthreads();   // also drains the NT zero stores (vmcnt(0)) before 1.0 writes

    // q_st output (reference order: x + (e - x)).
    float* outq = out + 1;
#pragma unroll
    for (int cc = 0; cc < 32; ++cc) {
        const int id = cc * 256 + tid;
        const int c = id >> 7, t = id & 127;
        const int kb = idx_sh[t];
        const float xv = xs[t * 68 + c];
        const float eq = E[kb * 64 + c];
        outq[((size_t)(b * 64 + c) << 12) + hw0 + t] = xv + (eq - xv);
    }
    // dw scatter-add: lane = dim (coalesced atomics), wave-uniform row.
#pragma unroll 4
    for (int tt = 0; tt < 32; ++tt) {
        const int t = w * 32 + tt;
        const int kb = idx_sh[t];
        atomicAdd(&ws[kb * 64 + lane], xs[t * 68 + lane]);
    }
    // one-hot encodings: rows pre-zeroed in the K-loop; write only the 1.0 entries.
    {
        if (tid < 128) {
            const int kb = idx_sh[tid];
            __builtin_nontemporal_store(1.0f, enc + (size_t)(tok0 + tid) * 1024 + kb);
        }
    }
}

// new_cs (Laplace-smoothed) + loss. 1 block x 1024.
__global__ __launch_bounds__(1024) void fin_cs(const float* __restrict__ cs_in,
                                               float* __restrict__ out,
                                               const float* __restrict__ ws) {
    __shared__ float red[16];
    __shared__ float n_sh;
    const int tid = threadIdx.x;
    const float raw = cs_in[tid] * DECAYF + ONEMF * ws[WS_COUNTS + tid];
    const float s = wave_reduce_add(raw);
    if ((tid & 63) == 0) red[tid >> 6] = s;
    __syncthreads();
    if (tid == 0) {
        float n = 0.f;
#pragma unroll
        for (int i = 0; i < 16; ++i) n += red[i];
        n_sh = n;
        out[0] = 0.25f * ws[WS_SSE] * (1.0f / 4194304.0f);  // loss
    }
    __syncthreads();
    const float n = n_sh;
    out[71368705 + tid] = (raw + EPSF) / (n + 1024.0f * EPSF) * n;
}

// new_ema_weight and new_embedding. grid 256 x 256.
__global__ __launch_bounds__(256) void fin_w(const float* __restrict__ emaw,
                                             float* __restrict__ out,
                                             const float* __restrict__ ws) {
    const int i = blockIdx.x * 256 + threadIdx.x;
    const float val = emaw[i] * DECAYF + ONEMF * ws[i];
    out[71369729 + i] = val;                               // new_ema_weight
    const float cs = out[71368705 + (i >> 6)];             // new_cs (from fin_cs)
    out[71303169 + i] = val / cs;                          // new_embedding
}

extern "C" void kernel_launch(void* const* d_in, const int* in_sizes, int n_in,
                              void* d_out, int out_size, void* d_ws, size_t ws_size,
                              hipStream_t stream) {
    const float* x    = (const float*)d_in[0];   // [16,64,64,64]
    const float* E    = (const float*)d_in[1];   // [1024,64]
    const float* cs   = (const float*)d_in[2];   // [1024]
    const float* emaw = (const float*)d_in[3];   // [1024,64]
    float* out = (float*)d_out;
    float* ws  = (float*)d_ws;

    prep_kernel<<<256, 256, 0, stream>>>(E, ws);
    vq_main<<<512, 256, 0, stream>>>(x, E, out, ws);
    fin_cs<<<1, 1024, 0, stream>>>(cs, out, ws);
    fin_w<<<256, 256, 0, stream>>>(emaw, out, ws);
}